// Round 10
// baseline (961.271 us; speedup 1.0000x reference)
//
#include <hip/hip_runtime.h>
#include <hip/hip_bf16.h>

typedef _Float16 f16;
typedef _Float16 f16x8 __attribute__((ext_vector_type(8)));
typedef _Float16 f16x4 __attribute__((ext_vector_type(4)));
typedef _Float16 f16x2 __attribute__((ext_vector_type(2)));
typedef float f32x4 __attribute__((ext_vector_type(4)));
typedef unsigned long long ull;

#define B_ 64
#define T_ 32
#define L_ 49
#define F_ 512
#define H_ 512
#define A_ 256
#define E_ 256
#define V_ 32000
#define G4 2048
#define NG 32       // slice blocks (16 hidden = 64 permuted cols each)
#define NLOG 125    // logit blocks (256 cols each), t-chunk = 2
#define SLOT 16

#define ALOAD32(p)     __hip_atomic_load((const unsigned*)(p), __ATOMIC_RELAXED, __HIP_MEMORY_SCOPE_AGENT)
#define ASTORE32(p, v) __hip_atomic_store((unsigned*)(p), (v), __ATOMIC_RELAXED, __HIP_MEMORY_SCOPE_AGENT)
#define ASTORE64(p, v) __hip_atomic_store((ull*)(p), (v), __ATOMIC_RELAXED, __HIP_MEMORY_SCOPE_AGENT)
#define AADD(p)        __hip_atomic_fetch_add((unsigned*)(p), 1u, __ATOMIC_RELAXED, __HIP_MEMORY_SCOPE_AGENT)

#if defined(__has_builtin)
#if __has_builtin(__builtin_amdgcn_fdot2)
#define HAS_FDOT2 1
#endif
#endif

// ================================================================ fused prologue
#define NB_TC0 (64 * 24)     // W_ih  -> WihT  [2048][768]
#define NB_TC1 (64 * 16)     // W_hh  -> WhhT  [2048][512]
#define NB_TC2 (1000 * 16)   // W_out -> WoutT [32000][512]
#define NB_TC3 (8 * 16)      // W_hid -> WhidT [256][512]
#define NB_CVT 1568
#define NB_EMB 2048
#define NB_INIT 64
#define NB_FP  196

__device__ void dev_tcvt(const float* __restrict__ x, f16* __restrict__ y,
                         int R, int C, int bx, int by, char* smem) {
    float (*ls)[33] = (float(*)[33])smem;
    int c0 = bx * 32, r0 = by * 32;
    int tid = threadIdx.x;
    int rr = tid >> 3, cs = (tid & 7) * 4;
    float4 v = *(const float4*)&x[(size_t)(r0 + rr) * C + c0 + cs];
    ls[rr][cs] = v.x; ls[rr][cs + 1] = v.y; ls[rr][cs + 2] = v.z; ls[rr][cs + 3] = v.w;
    __syncthreads();
    int cr = tid >> 3, rs = (tid & 7) * 4;
    f16x4 o = {(f16)ls[rs][cr], (f16)ls[rs + 1][cr], (f16)ls[rs + 2][cr], (f16)ls[rs + 3][cr]};
    *(f16x4*)&y[(size_t)(c0 + cr) * R + r0 + rs] = o;
}

__global__ __launch_bounds__(256) void k_prep(
    const float* __restrict__ image_feats, const int* __restrict__ caption,
    const float* __restrict__ embedding,
    const float* __restrict__ W_init_h, const float* __restrict__ b_init_h,
    const float* __restrict__ W_init_c, const float* __restrict__ b_init_c,
    const float* __restrict__ W_feat, const float* __restrict__ b_feat,
    const float* __restrict__ W_hid, const float* __restrict__ W_ih,
    const float* __restrict__ W_hh, const float* __restrict__ W_out,
    f16* __restrict__ feats16, f16* __restrict__ embs16,
    f16* __restrict__ WihT, f16* __restrict__ WhhT,
    f16* __restrict__ WoutT, f16* __restrict__ WhidT,
    f16* __restrict__ hslab, float* __restrict__ c_cur,
    float* __restrict__ featproj) {
    __shared__ __align__(16) char smem[32768];
    int bid = blockIdx.x, tid = threadIdx.x;
    int r = bid;
    if (r < NB_TC0) { dev_tcvt(W_ih, WihT, E_ + F_, G4, r % 64, r / 64, smem); return; }
    r -= NB_TC0;
    if (r < NB_TC1) { dev_tcvt(W_hh, WhhT, H_, G4, r % 64, r / 64, smem); return; }
    r -= NB_TC1;
    if (r < NB_TC2) { dev_tcvt(W_out, WoutT, H_, V_, r % 1000, r / 1000, smem); return; }
    r -= NB_TC2;
    if (r < NB_TC3) { dev_tcvt(W_hid, WhidT, H_, A_, r % 8, r / 8, smem); return; }
    r -= NB_TC3;
    if (r < NB_CVT) {
        int i = r * 256 + tid;
        float4 v = ((const float4*)image_feats)[i];
        f16x4 h = {(f16)v.x, (f16)v.y, (f16)v.z, (f16)v.w};
        ((f16x4*)feats16)[i] = h;
        return;
    }
    r -= NB_CVT;
    if (r < NB_EMB) {
        int tok = caption[r];
        embs16[(size_t)r * E_ + tid] = (f16)embedding[(size_t)tok * E_ + tid];
        return;
    }
    r -= NB_EMB;
    if (r < NB_INIT) {
        float* mean = (float*)smem;
        int b = r;
        for (int f = tid; f < F_; f += 256) {
            float s = 0.f;
            for (int l = 0; l < L_; ++l) s += image_feats[((size_t)b * L_ + l) * F_ + f];
            mean[f] = s * (1.f / 49.f);
        }
        __syncthreads();
        for (int h = tid; h < H_; h += 256) {
            float a = b_init_h[h], c = b_init_c[h];
            for (int k = 0; k < F_; ++k) {
                float m = mean[k];
                a += m * W_init_h[k * H_ + h];
                c += m * W_init_c[k * H_ + h];
            }
            hslab[(size_t)b * H_ + h] = (f16)a;
            c_cur[b * H_ + h] = c;
        }
        return;
    }
    r -= NB_INIT;
    {
        float (*fs)[F_] = (float(*)[F_])smem;
        int r0 = r * 16;
        for (int i = tid; i < 16 * F_; i += 256)
            fs[i >> 9][i & 511] = image_feats[(size_t)r0 * F_ + i];
        __syncthreads();
        float acc[16];
#pragma unroll
        for (int q = 0; q < 16; ++q) acc[q] = 0.f;
        for (int k = 0; k < F_; ++k) {
            float w = W_feat[k * A_ + tid];
#pragma unroll
            for (int q = 0; q < 16; ++q) acc[q] += fs[q][k] * w;
        }
        float bb = b_feat[tid];
#pragma unroll
        for (int q = 0; q < 16; ++q) featproj[(size_t)(r0 + q) * A_ + tid] = acc[q] + bb;
    }
}

// ================================================================ prologue GEMMs (gate-permuted f16 out)
struct Smem128 { f16 As[128][40]; f16 Bs[128][40]; };

__device__ __forceinline__ void gemm128_body1(
    const f16* __restrict__ A, int lda, const f16* __restrict__ Bt, int ldb,
    f16* __restrict__ Cv, int M, int K, int mtiles, int bid,
    const float* __restrict__ bias0, const float* __restrict__ bias1, Smem128* sm) {
    int m0 = (bid % mtiles) * 128, n0 = (bid / mtiles) * 128;
    int tid = threadIdx.x, lane = tid & 63, wave = tid >> 6;
    int wr = (wave >> 1) * 64, wc = (wave & 1) * 64;
    int frow = lane & 15, fk = (lane >> 4) * 8;
    int ra = tid >> 2, ka = (tid & 3) * 8;
    f32x4 acc[4][4];
#pragma unroll
    for (int i = 0; i < 4; ++i)
#pragma unroll
        for (int j = 0; j < 4; ++j) { acc[i][j][0]=0.f; acc[i][j][1]=0.f; acc[i][j][2]=0.f; acc[i][j][3]=0.f; }

    for (int k0 = 0; k0 < K; k0 += 32) {
        f16x8 a0 = *(const f16x8*)&A[(size_t)(m0 + ra) * lda + k0 + ka];
        f16x8 a1 = *(const f16x8*)&A[(size_t)(m0 + 64 + ra) * lda + k0 + ka];
        f16x8 b0 = *(const f16x8*)&Bt[(size_t)(n0 + ra) * ldb + k0 + ka];
        f16x8 b1 = *(const f16x8*)&Bt[(size_t)(n0 + 64 + ra) * ldb + k0 + ka];
        __syncthreads();
        *(f16x8*)&sm->As[ra][ka] = a0;
        *(f16x8*)&sm->As[64 + ra][ka] = a1;
        *(f16x8*)&sm->Bs[ra][ka] = b0;
        *(f16x8*)&sm->Bs[64 + ra][ka] = b1;
        __syncthreads();
        f16x8 av[4], bv[4];
#pragma unroll
        for (int i = 0; i < 4; ++i) {
            av[i] = *(f16x8*)&sm->As[wr + i * 16 + frow][fk];
            bv[i] = *(f16x8*)&sm->Bs[wc + i * 16 + frow][fk];
        }
#pragma unroll
        for (int mi = 0; mi < 4; ++mi)
#pragma unroll
            for (int ni = 0; ni < 4; ++ni)
                acc[mi][ni] = __builtin_amdgcn_mfma_f32_16x16x32_f16(av[mi], bv[ni], acc[mi][ni], 0, 0, 0);
    }
    int rq = (lane >> 4) * 4;
#pragma unroll
    for (int mi = 0; mi < 4; ++mi)
#pragma unroll
        for (int ni = 0; ni < 4; ++ni) {
            int cc = n0 + wc + ni * 16 + frow;
            float badd = (bias0 ? bias0[cc] : 0.f) + (bias1 ? bias1[cc] : 0.f);
#pragma unroll
            for (int r = 0; r < 4; ++r) {
                int rr = m0 + wr + mi * 16 + rq + r;
                if (rr < M)
                    Cv[((size_t)rr * 512 + (cc & 511)) * 4 + (cc >> 9)] =
                        (f16)(acc[mi][ni][r] + badd);
            }
        }
}

__global__ __launch_bounds__(256) void k_gemm_pre(
    int split,
    const f16* A0, int lda0, const f16* B0, int ldb0, f16* C0, int M0, int K0, int mt0,
    const f16* A1, int lda1, const f16* B1, int ldb1, f16* C1, int M1, int K1, int mt1,
    const float* bias0, const float* bias1) {
    __shared__ Smem128 sm;
    int bid = blockIdx.x;
    if (bid < split)
        gemm128_body1(A0, lda0, B0, ldb0, C0, M0, K0, mt0, bid,
                      (const float*)nullptr, (const float*)nullptr, &sm);
    else
        gemm128_body1(A1, lda1, B1, ldb1, C1, M1, K1, mt1, bid - split,
                      bias0, bias1, &sm);
}

// ================================================================ persistent kernel
// 64 gate blocks : attention + softmax + gsum = ep + sum_l alpha*fp2 (publish f16)
// 32 slice blocks: hw = h @ Whh-slice (overlaps gates), + gsum, LSTM pointwise,
//                  c in registers, publish own 16-hidden h-slice.
// 125 logit blocks: 256-col W_out tile, t-chunks of 2 (halves W_out refetch).
struct GateSm {
    float fp[L_][A_];
    float ea[A_];
    float ws[A_];
    float sc[64];
    float alpha[64];
    unsigned hL[256];
};
struct SliceSm {
    f16 w[64][512];          // XOR-swizzled 16B chunks by row&7
    union {
        f16 hs[64][512];     // A-stage (swizzled)
        float hwT[64][68];   // post-MFMA transpose (f32)
    } u;
};
struct LogSm { f16 hs[128][512]; };   // two steps' h, swizzled

__device__ __forceinline__ void wait_cnt(const unsigned* p, unsigned target) {
    if (threadIdx.x == 0) {
        while (ALOAD32(p) < target) __builtin_amdgcn_s_sleep(1);
    }
    __syncthreads();
    asm volatile("" ::: "memory");
}

__device__ __forceinline__ float sigm(float x) { return 1.f / (1.f + __expf(-x)); }
__device__ __forceinline__ float tanh_f(float x) { return 1.f - 2.f / (1.f + __expf(2.f * x)); }

__global__ __launch_bounds__(256, 1) void k_steps(
    const f16* __restrict__ WhhT, const f16* __restrict__ WhidT,
    const float* __restrict__ featproj, const float* __restrict__ b_hid,
    const float* __restrict__ W_score, const float* __restrict__ b_score,
    const f16* __restrict__ embP, const f16* __restrict__ fp2P,
    const float* __restrict__ c_cur,
    f16* __restrict__ hslab, f16* __restrict__ gsumP,
    const f16* __restrict__ WoutT, const float* __restrict__ b_out,
    float* __restrict__ preds, float* __restrict__ out_alpha,
    unsigned* __restrict__ cntH, unsigned* __restrict__ cntG,
    unsigned* __restrict__ cntH2) {
    __shared__ __align__(16) char smraw[sizeof(LogSm)];
    int bid = blockIdx.x, tid = threadIdx.x;

    if (bid < 64) {
        // ======== gate block for batch b: attention -> gsum ========
        int b = bid;
        GateSm* S = (GateSm*)smraw;
        for (int i = tid; i < L_ * A_; i += 256)
            ((float*)S->fp)[i] = featproj[(size_t)b * L_ * A_ + i];
        S->ws[tid] = W_score[tid];
        float bhid_r = b_hid[tid];
        float bsc = b_score[0];
        const f16* wrow = WhidT + (size_t)tid * 512;
        const unsigned* hsl32 = (const unsigned*)hslab;
        int wv = tid >> 6, ln = tid & 63;
        __syncthreads();

        for (int t = 0; t < T_; ++t) {
            if (t) wait_cnt(&cntH[t * SLOT], NG);
            S->hL[tid] = hsl32[((size_t)t * B_ + b) * 256 + tid];
            __syncthreads();
            // ---- ea = h @ W_hid + b_hid ----
            {
                float acc = bhid_r;
                const f16x8* hL8 = (const f16x8*)S->hL;
#pragma unroll 16
                for (int kk = 0; kk < 64; ++kk) {
                    union { f16x8 v; f16x2 p[4]; } uw, uh;
                    uw.v = *(const f16x8*)&wrow[kk * 8];
                    uh.v = hL8[kk];
#ifdef HAS_FDOT2
                    acc = __builtin_amdgcn_fdot2(uw.p[0], uh.p[0], acc, false);
                    acc = __builtin_amdgcn_fdot2(uw.p[1], uh.p[1], acc, false);
                    acc = __builtin_amdgcn_fdot2(uw.p[2], uh.p[2], acc, false);
                    acc = __builtin_amdgcn_fdot2(uw.p[3], uh.p[3], acc, false);
#else
#pragma unroll
                    for (int e = 0; e < 8; ++e) acc += (float)uw.v[e] * (float)uh.v[e];
#endif
                }
                S->ea[tid] = acc;
            }
            __syncthreads();
            // ---- scores ----
            for (int l = wv; l < L_; l += 4) {
                float p = 0.f;
#pragma unroll
                for (int q = 0; q < 4; ++q) {
                    int j = ln + q * 64;
                    p += tanh_f(S->fp[l][j] + S->ea[j]) * S->ws[j];
                }
#pragma unroll
                for (int off = 32; off > 0; off >>= 1) p += __shfl_xor(p, off);
                if (ln == 0) S->sc[l] = p;
            }
            __syncthreads();
            // ---- softmax (wave 0) ----
            if (tid < 64) {
                float v = (tid < L_) ? S->sc[tid] + bsc : -3.4e38f;
                float m = v;
#pragma unroll
                for (int off = 32; off > 0; off >>= 1) m = fmaxf(m, __shfl_xor(m, off));
                float e = (tid < L_) ? __expf(v - m) : 0.f;
                float s = e;
#pragma unroll
                for (int off = 32; off > 0; off >>= 1) s += __shfl_xor(s, off);
                if (tid < L_) {
                    float al = e / s;
                    S->alpha[tid] = al;
                    out_alpha[((size_t)b * T_ + t) * L_ + tid] = al;
                }
            }
            __syncthreads();
            // ---- gsum = ep + sum_l alpha*fp2 -> publish f16 ----
            {
                float s8[8];
#pragma unroll
                for (int i = 0; i < 8; ++i) s8[i] = 0.f;
                const f16* fpb = fp2P + (size_t)b * L_ * G4 + 8 * tid;
#pragma unroll 7
                for (int l = 0; l < L_; ++l) {
                    float a = S->alpha[l];
                    f16x8 fv = *(const f16x8*)&fpb[(size_t)l * G4];
#pragma unroll
                    for (int i = 0; i < 8; ++i) s8[i] += a * (float)fv[i];
                }
                f16x8 ep = *(const f16x8*)&embP[((size_t)b * T_ + t) * G4 + 8 * tid];
                union { f16 h[8]; ull u[2]; } pk;
#pragma unroll
                for (int i = 0; i < 8; ++i) pk.h[i] = (f16)((float)ep[i] + s8[i]);
                ull* gdst = (ull*)&gsumP[((size_t)t * B_ + b) * G4 + 8 * tid];
                ASTORE64(gdst, pk.u[0]);
                ASTORE64(gdst + 1, pk.u[1]);
            }
            __syncthreads();   // drains vmcnt: gsum stores acked
            if (tid == 0) AADD(&cntG[t * SLOT]);
        }
    } else if (bid < 64 + NG) {
        // ======== slice block g: hidden j in [16g,16g+16) ========
        int g = bid - 64;
        SliceSm* S = (SliceSm*)smraw;
        for (int i = 0; i < 16; ++i) {
            int idx = i * 256 + tid;
            int r = idx >> 6, ch = idx & 63;
            int cc = (r & 3) * 512 + 16 * g + (r >> 2);
            *(f16x8*)&S->w[r][(ch ^ (r & 7)) * 8] =
                *(const f16x8*)&WhhT[(size_t)cc * 512 + ch * 8];
        }
        int wvv = tid >> 6, lane = tid & 63;
        int frow = lane & 15, q = lane >> 4, sw = frow & 7, rq = q * 4;
        int b = tid >> 2, quad = tid & 3;
        float cr[4];
#pragma unroll
        for (int d = 0; d < 4; ++d)
            cr[d] = c_cur[b * H_ + 16 * g + 4 * quad + d];
        __syncthreads();

        for (int t = 0; t < T_; ++t) {
            if (t) wait_cnt(&cntH[t * SLOT], NG);
            // gather h(t) (plain coalesced loads of fresh slab)
            {
                const f16* hsrc = hslab + (size_t)t * B_ * H_;
#pragma unroll
                for (int i = 0; i < 16; ++i) {
                    int idx = i * 256 + tid;
                    int r = idx >> 6, ch = idx & 63;
                    *(f16x8*)&S->u.hs[r][(ch ^ (r & 7)) * 8] =
                        *(const f16x8*)&hsrc[(size_t)r * H_ + ch * 8];
                }
            }
            __syncthreads();
            f32x4 a4[4];
#pragma unroll
            for (int mi = 0; mi < 4; ++mi) { a4[mi][0]=0.f; a4[mi][1]=0.f; a4[mi][2]=0.f; a4[mi][3]=0.f; }
#pragma unroll
            for (int kk = 0; kk < 16; ++kk) {
                int ch = ((kk * 4 + q) ^ sw) * 8;
                f16x8 bv = *(f16x8*)&S->w[wvv * 16 + frow][ch];
#pragma unroll
                for (int mi = 0; mi < 4; ++mi) {
                    f16x8 av = *(f16x8*)&S->u.hs[mi * 16 + frow][ch];
                    a4[mi] = __builtin_amdgcn_mfma_f32_16x16x32_f16(av, bv, a4[mi], 0, 0, 0);
                }
            }
            // wait gsum (barrier also drains the hs LDS reads before overwrite)
            wait_cnt(&cntG[t * SLOT], 64);
#pragma unroll
            for (int mi = 0; mi < 4; ++mi)
#pragma unroll
                for (int r = 0; r < 4; ++r)
                    S->u.hwT[mi * 16 + rq + r][wvv * 16 + frow] = a4[mi][r];
            __syncthreads();
            // ---- gates + pointwise; thread owns (b, hidden 16g+4*quad+0..3) ----
            {
                const f16* gp = &gsumP[((size_t)t * B_ + b) * G4 + 64 * g + 16 * quad];
                f16x8 q0 = *(const f16x8*)gp;
                f16x8 q1 = *(const f16x8*)(gp + 8);
                float gl[16];
#pragma unroll
                for (int i = 0; i < 8; ++i) { gl[i] = (float)q0[i]; gl[8 + i] = (float)q1[i]; }
                const float* hwrow = &S->u.hwT[b][16 * quad];
                f16 hv[4];
#pragma unroll
                for (int d = 0; d < 4; ++d) {
                    float gi = hwrow[4 * d]     + gl[4 * d];
                    float gf = hwrow[4 * d + 1] + gl[4 * d + 1];
                    float gg = hwrow[4 * d + 2] + gl[4 * d + 2];
                    float go = hwrow[4 * d + 3] + gl[4 * d + 3];
                    float cn = sigm(gf) * cr[d] + sigm(gi) * tanh_f(gg);
                    float hn = sigm(go) * tanh_f(cn);
                    cr[d] = cn;
                    hv[d] = (f16)hn;
                }
                union { f16 h[4]; ull u; } ph;
                *(f16x4*)ph.h = *(f16x4*)hv;
                ASTORE64((ull*)&hslab[((size_t)(t + 1) * B_ + b) * H_ + 16 * g + 4 * quad], ph.u);
            }
            __syncthreads();   // drains vmcnt: h stores acked
            if (tid == 0) {
                AADD(&cntH[(t + 1) * SLOT]);
                AADD(&cntH2[(t + 1) * SLOT]);
            }
        }
    } else {
        // ======== logit block: W_out cols [nt*256, nt*256+256), t-chunks of 2 ========
        int nt = bid - 64 - NG;
        int n0 = nt * 256;
        LogSm* S = (LogSm*)smraw;
        int wvv = tid >> 6, lane = tid & 63;
        int frow = lane & 15, q = lane >> 4, sw = frow & 7, rq = q * 4;

        for (int tc = 0; tc < T_ / 2; ++tc) {
            wait_cnt(&cntH2[(2 * tc + 2) * SLOT], NG);
            {
                const f16* hsrc = hslab + (size_t)(2 * tc + 1) * B_ * H_;
#pragma unroll
                for (int i = 0; i < 32; ++i) {
                    int idx = i * 256 + tid;
                    int r = idx >> 6, ch = idx & 63;
                    *(f16x8*)&S->hs[r][(ch ^ (r & 7)) * 8] =
                        *(const f16x8*)&hsrc[(size_t)r * H_ + ch * 8];
                }
            }
            __syncthreads();
            f32x4 acc[8][4];
#pragma unroll
            for (int mi = 0; mi < 8; ++mi)
#pragma unroll
                for (int ni = 0; ni < 4; ++ni) { acc[mi][ni][0]=0.f; acc[mi][ni][1]=0.f; acc[mi][ni][2]=0.f; acc[mi][ni][3]=0.f; }
#pragma unroll 2
            for (int kk = 0; kk < 16; ++kk) {
                int ch = ((kk * 4 + q) ^ sw) * 8;
                f16x8 av[8], bv[4];
#pragma unroll
                for (int mi = 0; mi < 8; ++mi)
                    av[mi] = *(f16x8*)&S->hs[mi * 16 + frow][ch];
#pragma unroll
                for (int ni = 0; ni < 4; ++ni)
                    bv[ni] = *(const f16x8*)&WoutT[(size_t)(n0 + wvv * 64 + ni * 16 + frow) * 512 + kk * 32 + q * 8];
#pragma unroll
                for (int mi = 0; mi < 8; ++mi)
#pragma unroll
                    for (int ni = 0; ni < 4; ++ni)
                        acc[mi][ni] = __builtin_amdgcn_mfma_f32_16x16x32_f16(av[mi], bv[ni], acc[mi][ni], 0, 0, 0);
            }
#pragma unroll
            for (int ni = 0; ni < 4; ++ni) {
                int cc = n0 + wvv * 64 + ni * 16 + frow;
                float badd = b_out[cc];
#pragma unroll
                for (int mi = 0; mi < 8; ++mi)
#pragma unroll
                    for (int r = 0; r < 4; ++r) {
                        int rr = mi * 16 + rq + r;
                        int tt = 2 * tc + (rr >> 6), bb2 = rr & 63;
                        preds[((size_t)bb2 * T_ + tt) * V_ + cc] = acc[mi][ni][r] + badd;
                    }
            }
            __syncthreads();   // MFMA hs reads done before next chunk's gather
        }
    }
}

// ================================================================ launch
extern "C" void kernel_launch(void* const* d_in, const int* in_sizes, int n_in,
                              void* d_out, int out_size, void* d_ws, size_t ws_size,
                              hipStream_t stream) {
    const float* image_feats = (const float*)d_in[0];
    const int*   caption     = (const int*)d_in[1];
    const float* embedding   = (const float*)d_in[2];
    const float* W_init_h    = (const float*)d_in[3];
    const float* b_init_h    = (const float*)d_in[4];
    const float* W_init_c    = (const float*)d_in[5];
    const float* b_init_c    = (const float*)d_in[6];
    const float* W_feat      = (const float*)d_in[7];
    const float* b_feat      = (const float*)d_in[8];
    const float* W_hid       = (const float*)d_in[9];
    const float* b_hid       = (const float*)d_in[10];
    const float* W_score     = (const float*)d_in[11];
    const float* b_score     = (const float*)d_in[12];
    const float* W_ih        = (const float*)d_in[13];
    const float* b_ih        = (const float*)d_in[14];
    const float* W_hh        = (const float*)d_in[15];
    const float* b_hh        = (const float*)d_in[16];
    const float* W_out       = (const float*)d_in[17];
    const float* b_out       = (const float*)d_in[18];

    float* preds = (float*)d_out;                                   // (B,T,V)
    float* out_alpha = preds + (size_t)B_ * T_ * V_;                // (B,T,L)

    size_t off = 0;
    char* base = (char*)d_ws;
    auto carve = [&](size_t bytes) {
        void* p = base + off;
        off += (bytes + 255) & ~(size_t)255;
        return p;
    };
    const int MP = 3200;
    f16* fp2P       = (f16*)carve((size_t)MP * G4 * 2);             // 13.1 MB
    f16* embP       = (f16*)carve((size_t)B_ * T_ * G4 * 2);        // 8.4 MB
    float* featproj = (float*)carve((size_t)B_ * L_ * A_ * 4);      // 3.2 MB
    float* c_cur    = (float*)carve((size_t)B_ * H_ * 4);
    f16* hslab      = (f16*)carve((size_t)(T_ + 1) * B_ * H_ * 2);  // 2.1 MB
    f16* gsumP      = (f16*)carve((size_t)T_ * B_ * G4 * 2);        // 8.4 MB
    unsigned* cnts  = (unsigned*)carve(3 * (T_ + 2) * SLOT * 4);
    f16* feats16    = (f16*)carve((size_t)MP * F_ * 2);
    f16* embs16     = (f16*)carve((size_t)B_ * T_ * E_ * 2);
    f16* WihT       = (f16*)carve((size_t)G4 * (E_ + F_) * 2);
    f16* WhhT       = (f16*)carve((size_t)G4 * H_ * 2);
    f16* WoutT      = (f16*)carve((size_t)V_ * H_ * 2);
    f16* WhidT      = (f16*)carve((size_t)A_ * H_ * 2);
    unsigned* cntH  = cnts;
    unsigned* cntG  = cnts + (T_ + 2) * SLOT;
    unsigned* cntH2 = cnts + 2 * (T_ + 2) * SLOT;
    (void)ws_size; (void)in_sizes; (void)n_in; (void)out_size;

    // 1) fused prologue
    {
        int nb = NB_TC0 + NB_TC1 + NB_TC2 + NB_TC3 + NB_CVT + NB_EMB + NB_INIT + NB_FP;
        hipLaunchKernelGGL(k_prep, dim3(nb), dim3(256), 0, stream,
                           image_feats, caption, embedding,
                           W_init_h, b_init_h, W_init_c, b_init_c,
                           W_feat, b_feat, W_hid, W_ih, W_hh, W_out,
                           feats16, embs16, WihT, WhhT, WoutT, WhidT,
                           hslab, c_cur, featproj);
    }
    // 2) merged prologue GEMMs: fp2P (400 blocks) + embP (256 blocks)
    hipLaunchKernelGGL(k_gemm_pre, dim3(400 + 256), dim3(256), 0, stream,
                       400,
                       feats16, F_, WihT + E_, E_ + F_, fp2P, B_ * L_, F_, 25,
                       embs16, E_, WihT, E_ + F_, embP, B_ * T_, E_, B_ * T_ / 128,
                       b_ih, b_hh);
    // 3) reset counters
    hipMemsetAsync(cnts, 0, 3 * (T_ + 2) * SLOT * 4, stream);
    // 4) persistent recurrence + shadowed logits (221 blocks, co-resident)
    hipLaunchKernelGGL(k_steps, dim3(64 + NG + NLOG), dim3(256), 0, stream,
                       WhhT, WhidT, featproj, b_hid, W_score, b_score,
                       embP, fp2P, c_cur, hslab, gsumP,
                       WoutT, b_out, preds, out_alpha,
                       cntH, cntG, cntH2);
}